// Round 8
// baseline (240.436 us; speedup 1.0000x reference)
//
#include <hip/hip_runtime.h>
#include <math.h>

#define HW (512 * 512)
#define NB 16
#define NTHR 256
#define GXS 128         // blocks per batch: 128 blocks * 256 thr * 8 px = HW
#define CH 2            // chunks per thread (4 px each) = 8 px/thread
#define ACCW 56         // padded stride of the 53-value per-block partials

// ---- workspace layout (4-byte words). NOTHING is pre-zeroed: every word is
// written unconditionally before it is read (poison-robust). Coherence comes
// from kernel dispatch boundaries only — round-5 lesson: device-scope fences
// (threadfence/tickets) inside hot kernels cost ~2.5x via L2 writeback/inv. ----
#define OFF_ACC    0                            // f [NB][GXS][ACCW] k_stats partials
#define OFF_NEGMX  (OFF_ACC + NB * GXS * ACCW)  // u [NB][GXS] per-block max(~negkey)
#define OFF_PPART  (OFF_NEGMX + NB * GXS)       // f [NB][GXS][4] k_pix partials
#define OFF_KDICE  (OFF_PPART + NB * GXS * 4)   // f [NB][3] ak,bk,ck
#define OFF_NVAL   (OFF_KDICE + NB * 3)         // u [NB]
#define OFF_DISCR  (OFF_NVAL + NB)              // f [NB]

// partial value indices: 0-7 kcnt, 8-15 tcnt, 16-47 ksum, 48 pos,
//                        49 ak, 50 bk, 51 ck, 52 negcnt

__device__ __forceinline__ unsigned fmap(float f) {
    unsigned u = __float_as_uint(f);
    return (u & 0x80000000u) ? ~u : (u | 0x80000000u);
}
__device__ __forceinline__ float funmap(unsigned u) {
    return (u & 0x80000000u) ? __uint_as_float(u & 0x7FFFFFFFu)
                             : __uint_as_float(~u);
}
__device__ __forceinline__ float wred(float x) {
#pragma unroll
    for (int o = 32; o; o >>= 1) x += __shfl_xor(x, o);
    return x;
}
__device__ __forceinline__ unsigned wredumax(unsigned x) {
#pragma unroll
    for (int o = 32; o; o >>= 1) x = max(x, (unsigned)__shfl_xor((int)x, o));
    return x;
}
__device__ __forceinline__ unsigned long long wredull(unsigned long long x) {
#pragma unroll
    for (int o = 32; o; o >>= 1)
        x += (unsigned long long)__shfl_xor((unsigned long long)x, o);
    return x;
}

// ---------------- K1: stats + kernel-dice partials ----------------
// Round-7 body (proven correct, zero spill at 64 VGPR) with the grid doubled:
// round-7 counters showed the memory path is the critical path (removing VALU
// work moved VALUBusy 22->18% but not duration) and occupancy was GRID-capped
// at 16 waves/CU (40% measured). 64 VGPR permits 8 waves/SIMD; GXS=128 supplies
// them. Round-4's version of this experiment was invalidated by lb(,4) spills
// (27 MB scratch) — lb(,2) keeps the relaxed allocation.
__global__ __launch_bounds__(NTHR, 2) void k_stats(const float* __restrict__ preds,
                        const int* __restrict__ text,
                        const int* __restrict__ kern,
                        const int* __restrict__ mask,
                        unsigned* __restrict__ wsu) {
    float* wsf = (float*)wsu;
    const int b = blockIdx.y;
    const int tid = threadIdx.x;
    const int lane = tid & 63;
    __shared__ float sacc[53];
    __shared__ unsigned smx;
    if (tid < 53) sacc[tid] = 0.f;
    if (tid == 0) smx = 0u;
    __syncthreads();

    const int* tb = text + b * HW;
    const int* kb = kern + b * HW;
    const int* mb = mask + b * HW;
    const float* p0 = preds + (size_t)(b * 6 + 0) * HW;
    const float* p1 = preds + (size_t)(b * 6 + 1) * HW;
    const float* e0 = preds + (size_t)(b * 6 + 2) * HW;
    const float* e1 = e0 + HW;
    const float* e2 = e0 + 2 * HW;
    const float* e3 = e0 + 3 * HW;

    unsigned negc = 0u;   // per-thread count of text==0 pixels
    unsigned mkAll = 0u;

    float ks[32];
#pragma unroll
    for (int i = 0; i < 32; i++) ks[i] = 0.f;
    float r_ak = 0.f, r_bk = 0.f, r_ck = 0.f, r_pos = 0.f;
    unsigned kcW[8] = {0, 0, 0, 0, 0, 0, 0, 0};
    unsigned long long tpack = 0ull;  // 8x8-bit per-thread text-counts (<=8/field)

#pragma unroll 1
    for (int c = 0; c < CH; c++) {
        const int base = blockIdx.x * (NTHR * 4 * CH) + c * (NTHR * 4) + tid * 4;
        const int4 t4 = *(const int4*)(tb + base);
        const int4 k4 = *(const int4*)(kb + base);
        const int4 m4 = *(const int4*)(mb + base);
        const float4 s4 = *(const float4*)(p0 + base);
        const float4 q4 = *(const float4*)(p1 + base);
        const float4 a4 = *(const float4*)(e0 + base);
        const float4 b4 = *(const float4*)(e1 + base);
        const float4 c4 = *(const float4*)(e2 + base);
        const float4 d4 = *(const float4*)(e3 + base);

#define PIX(T, K, M, Q, A, B, C, D) do {                                     \
        bool pos_ = (T) > 0, mp_ = (M) > 0;                                  \
        float sm_ = (pos_ && mp_) ? 1.f : 0.f;                               \
        float sg_ = 1.f / (1.f + expf(-(Q)));                                \
        float ik_ = ((K) > 0) ? 1.f : 0.f;                                   \
        r_ak += sm_ * sg_ * ik_;                                             \
        r_bk += sm_ * sg_ * sg_;                                             \
        r_ck += sm_ * ik_;                                                   \
        r_pos += sm_;                                                        \
        tpack += pos_ ? (1ull << ((((unsigned)(T) - 1u) & 7u) * 8u)) : 0ull; \
        _Pragma("unroll")                                                    \
        for (int i_ = 0; i_ < 8; i_++) {                                     \
            bool hit_ = ((K) == i_ + 1);                                     \
            kcW[i_] += (unsigned)__popcll(__ballot(hit_));                   \
            float h_ = hit_ ? 1.f : 0.f;                                     \
            ks[i_ * 4 + 0] += h_ * (A);                                      \
            ks[i_ * 4 + 1] += h_ * (B);                                      \
            ks[i_ * 4 + 2] += h_ * (C);                                      \
            ks[i_ * 4 + 3] += h_ * (D);                                      \
        }                                                                    \
    } while (0)

        PIX(t4.x, k4.x, m4.x, q4.x, a4.x, b4.x, c4.x, d4.x);
        PIX(t4.y, k4.y, m4.y, q4.y, a4.y, b4.y, c4.y, d4.y);
        PIX(t4.z, k4.z, m4.z, q4.z, a4.z, b4.z, c4.z, d4.z);
        PIX(t4.w, k4.w, m4.w, q4.w, a4.w, b4.w, c4.w, d4.w);
#undef PIX

        // ---- per-thread negative count + min negative score (no ballots) ----
        negc += (unsigned)(t4.x == 0) + (unsigned)(t4.y == 0)
              + (unsigned)(t4.z == 0) + (unsigned)(t4.w == 0);
        unsigned mk = 0u;
        if (t4.x == 0) mk = max(mk, ~fmap(s4.x));
        if (t4.y == 0) mk = max(mk, ~fmap(s4.y));
        if (t4.z == 0) mk = max(mk, ~fmap(s4.z));
        if (t4.w == 0) mk = max(mk, ~fmap(s4.w));
        mkAll = max(mkAll, mk);
    }

    mkAll = wredumax(mkAll);
    if (lane == 0) atomicMax(&smx, mkAll);

    // ---- epilogue: wave butterfly -> LDS -> plain per-block store ----
#pragma unroll
    for (int i = 0; i < 32; i++) {
        float v = wred(ks[i]);
        if (lane == 0) atomicAdd(&sacc[16 + i], v);
    }
    {
        float v = wred(r_ak); if (lane == 0) atomicAdd(&sacc[49], v);
        v = wred(r_bk); if (lane == 0) atomicAdd(&sacc[50], v);
        v = wred(r_ck); if (lane == 0) atomicAdd(&sacc[51], v);
        v = wred(r_pos); if (lane == 0) atomicAdd(&sacc[48], v);
        unsigned nv = negc;   // per-thread counts -> butterfly is correct here
#pragma unroll
        for (int o = 32; o; o >>= 1) nv += (unsigned)__shfl_xor((int)nv, o);
        if (lane == 0) atomicAdd(&sacc[52], (float)nv);
    }
    {
        // unpack 8x8-bit -> 2x(4x16-bit) so the 64-lane sum can't overflow
        unsigned long long lo = tpack & 0x00FF00FF00FF00FFull;          // inst 1,3,5,7
        unsigned long long hi = (tpack >> 8) & 0x00FF00FF00FF00FFull;   // inst 2,4,6,8
        lo = wredull(lo);
        hi = wredull(hi);
        if (lane == 0) {
            atomicAdd(&sacc[8 + 0], (float)(unsigned)( lo        & 0xFFFFull));
            atomicAdd(&sacc[8 + 2], (float)(unsigned)((lo >> 16) & 0xFFFFull));
            atomicAdd(&sacc[8 + 4], (float)(unsigned)((lo >> 32) & 0xFFFFull));
            atomicAdd(&sacc[8 + 6], (float)(unsigned)((lo >> 48) & 0xFFFFull));
            atomicAdd(&sacc[8 + 1], (float)(unsigned)( hi        & 0xFFFFull));
            atomicAdd(&sacc[8 + 3], (float)(unsigned)((hi >> 16) & 0xFFFFull));
            atomicAdd(&sacc[8 + 5], (float)(unsigned)((hi >> 32) & 0xFFFFull));
            atomicAdd(&sacc[8 + 7], (float)(unsigned)((hi >> 48) & 0xFFFFull));
        }
    }
    if (lane == 0) {
#pragma unroll
        for (int i = 0; i < 8; i++) atomicAdd(&sacc[i], (float)kcW[i]);
    }
    __syncthreads();
    if (tid < 53)
        wsf[OFF_ACC + (b * GXS + blockIdx.x) * ACCW + tid] = sacc[tid];
    if (tid == 0)
        wsu[OFF_NEGMX + b * GXS + blockIdx.x] = smx;
}

// ---------------- K2: redundant per-batch setup + aggregation + OHEM dice ----
// Each block recomputes its batch's setup from k_stats partials (fence-free:
// the dispatch boundary guarantees visibility; the redundant work is L2-resident
// loads). bx==0 additionally writes KDICE/NVAL/DISCR for k_final.
__global__ __launch_bounds__(NTHR, 2) void k_pix(const float* __restrict__ preds,
                      const int* __restrict__ text,
                      const int* __restrict__ mask,
                      unsigned* __restrict__ wsu) {
    float* wsf = (float*)wsu;
    const int b = blockIdx.y;
    const int tid = threadIdx.x;
    const int lane = tid & 63;
    __shared__ float s_sum[53];
    __shared__ float stbl[45];
    __shared__ int s_valid[8];
    __shared__ unsigned s_negmax;
    __shared__ float s_thr;
    __shared__ int s_fb;
    __shared__ unsigned s_kk, s_prefix;
    __shared__ unsigned s_hist[256];
    __shared__ float sred[4];

    const int* tb = text + b * HW;
    const int* mb = mask + b * HW;
    const float* p0 = preds + (size_t)(b * 6) * HW;
    const float* e0 = preds + (size_t)(b * 6 + 2) * HW;
    const float* e1 = e0 + HW;
    const float* e2 = e0 + 2 * HW;
    const float* e3 = e0 + 3 * HW;

    // ---- preamble: recompute batch setup from partials ----
    if (tid < 53) {
        float v = 0.f;
        const float* p = wsf + OFF_ACC + (size_t)b * GXS * ACCW + tid;
        for (int r = 0; r < GXS; r++) v += p[r * ACCW];
        s_sum[tid] = v;
    }
    if (tid >= 64 && tid < 128) {
        // 64 threads cover GXS=128 entries, 2 each
        unsigned m = max(wsu[OFF_NEGMX + b * GXS + (tid - 64)],
                         wsu[OFF_NEGMX + b * GXS + (tid - 64) + 64]);
        m = wredumax(m);
        if (tid == 64) s_negmax = m;
    }
    if (tid < 4) sred[tid] = 0.f;
    __syncthreads();
    if (tid < 8) {
        float kcf = s_sum[tid];
        float tcf = s_sum[8 + tid];
        int valid = (kcf > 0.f && tcf > 0.f) ? 1 : 0;
        s_valid[tid] = valid;
        float inv = 1.f / fmaxf(kcf, 1.f);
        float w = valid ? 1.f / fmaxf(tcf, 1.f) : 0.f;
#pragma unroll
        for (int c = 0; c < 4; c++)
            stbl[(tid + 1) * 5 + c] = s_sum[16 + tid * 4 + c] * inv;
        stbl[(tid + 1) * 5 + 4] = w;
    }
    if (tid >= 8 && tid < 13) stbl[tid - 8] = 0.f;   // bg row
    __syncthreads();
    if (tid == 0) {
        unsigned pos = (unsigned)s_sum[48];
        unsigned neg = (unsigned)s_sum[52];
        unsigned nn = min(pos * 3u, neg);
        int fb = (pos == 0u || nn == 0u) ? 1 : 0;
        s_fb = fb;
        unsigned kk = fb ? 0u : nn;
        float thr = 0.f;
        if (!fb && nn == neg) {           // fast path: min negative score
            thr = funmap(~s_negmax);
            kk = 0u;
        }
        s_thr = thr;
        s_kk = kk;
        s_prefix = 0u;
    }
    // bx==0 block: housekeeping for k_final
    if (blockIdx.x == 0) {
        if (tid >= 16 && tid < 19)
            wsf[OFF_KDICE + b * 3 + (tid - 16)] = s_sum[49 + (tid - 16)];
        if (tid == 32) {
            int nval = 0;
            for (int i = 0; i < 8; i++) nval += s_valid[i];
            wsu[OFF_NVAL + b] = (unsigned)nval;
            float L = 0.f;
            for (int i = 0; i < 8; i++)
                for (int j = i + 1; j < 8; j++)
                    if (s_valid[i] && s_valid[j]) {
                        float sq = 0.f;
                        for (int c = 0; c < 4; c++) {
                            float d = stbl[(i + 1) * 5 + c] - stbl[(j + 1) * 5 + c];
                            sq += d * d;
                        }
                        float h = fmaxf(3.0f - sqrtf(sq), 0.f);
                        L += log1pf(h * h);
                    }
            wsf[OFF_DISCR + b] = (nval > 1) ? L / fmaxf((float)(nval * (nval - 1)), 1.f) : 0.f;
        }
    }
    __syncthreads();
    // rare fallback: per-block radix select over raw preds (correct, slow,
    // never taken on fast-path data)
    if (s_kk != 0u) {
        unsigned prefix = 0u;
        for (int pass = 0; pass < 4; pass++) {
            const int shift = 24 - 8 * pass;
            const unsigned fmask = (pass == 0) ? 0u : (0xFFFFFFFFu << (shift + 8));
            s_hist[tid] = 0u;
            __syncthreads();
            for (int p = tid; p < HW; p += NTHR) {
                if (tb[p] == 0) {
                    unsigned key = fmap(p0[p]);
                    if ((key & fmask) == prefix) atomicAdd(&s_hist[(key >> shift) & 255u], 1u);
                }
            }
            __syncthreads();
            if (tid == 0) {
                unsigned k2 = s_kk;
                for (int bin = 255; bin >= 0; --bin) {
                    unsigned c = s_hist[bin];
                    if (k2 <= c) { s_prefix = prefix | (((unsigned)bin) << shift); s_kk = k2; break; }
                    k2 -= c;
                }
            }
            __syncthreads();
            prefix = s_prefix;
        }
        if (tid == 0) s_thr = funmap(prefix);
        __syncthreads();
    }
    const float thr = s_thr;
    const bool fb = s_fb != 0;

    // ---- main loop: round-0 body ----
    float r_at = 0.f, r_bt = 0.f, r_ct = 0.f, r_ag = 0.f;
#pragma unroll 1
    for (int c = 0; c < CH; c++) {
        const int base = blockIdx.x * (NTHR * 4 * CH) + c * (NTHR * 4) + tid * 4;
        const int4 t4 = *(const int4*)(tb + base);
        const int4 m4 = *(const int4*)(mb + base);
        const float4 s4 = *(const float4*)(p0 + base);
        const float4 a4 = *(const float4*)(e0 + base);
        const float4 b4 = *(const float4*)(e1 + base);
        const float4 c4 = *(const float4*)(e2 + base);
        const float4 d4 = *(const float4*)(e3 + base);

#define PPIX(T, M, S, A, B, C, D) do {                                       \
        bool pos_ = (T) > 0;                                                 \
        bool samp_ = fb ? ((M) > 0) : ((((S) >= thr) || pos_) && ((M) > 0)); \
        float sg_ = 1.f / (1.f + expf(-(S)));                                \
        float smf_ = samp_ ? 1.f : 0.f;                                      \
        float it_ = pos_ ? 1.f : 0.f;                                        \
        r_at += smf_ * sg_ * it_;                                            \
        r_bt += smf_ * sg_ * sg_;                                            \
        r_ct += smf_ * it_;                                                  \
        int t5_ = min((T), 8) * 5;                                           \
        float d0_ = (A) - stbl[t5_ + 0];                                     \
        float d1_ = (B) - stbl[t5_ + 1];                                     \
        float d2_ = (C) - stbl[t5_ + 2];                                     \
        float d3_ = (D) - stbl[t5_ + 3];                                     \
        float w_ = stbl[t5_ + 4];                                            \
        float sq_ = d0_ * d0_ + d1_ * d1_ + d2_ * d2_ + d3_ * d3_;           \
        float dist_ = sqrtf(sq_ + 1e-12f) - 0.5f;                            \
        float hp_ = fmaxf(dist_, 0.f);                                       \
        r_ag += w_ * log1pf(hp_ * hp_);                                      \
    } while (0)

        PPIX(t4.x, m4.x, s4.x, a4.x, b4.x, c4.x, d4.x);
        PPIX(t4.y, m4.y, s4.y, a4.y, b4.y, c4.y, d4.y);
        PPIX(t4.z, m4.z, s4.z, a4.z, b4.z, c4.z, d4.z);
        PPIX(t4.w, m4.w, s4.w, a4.w, b4.w, c4.w, d4.w);
#undef PPIX
    }

    {
        float v = wred(r_at); if (lane == 0) atomicAdd(&sred[0], v);
        v = wred(r_bt); if (lane == 0) atomicAdd(&sred[1], v);
        v = wred(r_ct); if (lane == 0) atomicAdd(&sred[2], v);
        v = wred(r_ag); if (lane == 0) atomicAdd(&sred[3], v);
    }
    __syncthreads();
    if (tid < 4)
        wsf[OFF_PPART + (b * GXS + blockIdx.x) * 4 + tid] = sred[tid];
}

// ---------------- K3: final assembly ----------------
__global__ void k_final(unsigned* __restrict__ wsu, float* __restrict__ out) {
    float* wsf = (float*)wsu;
    __shared__ float sfin[64];
    __shared__ float lt[NB], lk[NB], la[NB], ld[NB];
    const int tid = threadIdx.x;   // 64 threads
    {
        const int bb = tid >> 2, v = tid & 3;
        float s = 0.f;
        const float* p = wsf + OFF_PPART + (size_t)bb * GXS * 4 + v;
        for (int r = 0; r < GXS; r++) s += p[r * 4];
        sfin[tid] = s;
    }
    __syncthreads();
    if (tid < NB) {
        const float S = 1e-3f;
        float at = sfin[tid * 4 + 0], bt = sfin[tid * 4 + 1];
        float ct = sfin[tid * 4 + 2], ag = sfin[tid * 4 + 3];
        float ak = wsf[OFF_KDICE + tid * 3 + 0];
        float bk = wsf[OFF_KDICE + tid * 3 + 1];
        float ck = wsf[OFF_KDICE + tid * 3 + 2];
        lt[tid] = 1.f - 2.f * (at + S) / ((bt + S) + (ct + S));
        lk[tid] = 1.f - 2.f * (ak + S) / ((bk + S) + (ck + S));
        int nval = (int)wsu[OFF_NVAL + tid];
        la[tid] = (nval > 0) ? ag / fmaxf((float)nval, 1.f) : 0.f;
        ld[tid] = wsf[OFF_DISCR + tid];
    }
    __syncthreads();
    if (tid == 0) {
        float st = 0, sk = 0, sa = 0, sd = 0;
        for (int i = 0; i < NB; i++) { st += lt[i]; sk += lk[i]; sa += la[i]; sd += ld[i]; }
        out[0] = st / NB;
        out[1] = 0.5f * sk / NB;
        out[2] = 0.25f * sa / NB;
        out[3] = 0.25f * sd / NB;
    }
}

extern "C" void kernel_launch(void* const* d_in, const int* in_sizes, int n_in,
                              void* d_out, int out_size, void* d_ws, size_t ws_size,
                              hipStream_t stream) {
    const float* preds = (const float*)d_in[0];
    const int* text = (const int*)d_in[1];
    const int* kern = (const int*)d_in[2];
    const int* mask = (const int*)d_in[3];
    unsigned* wsu = (unsigned*)d_ws;
    float* out = (float*)d_out;

    dim3 grid(GXS, NB);
    k_stats<<<grid, NTHR, 0, stream>>>(preds, text, kern, mask, wsu);
    k_pix<<<grid, NTHR, 0, stream>>>(preds, text, mask, wsu);
    k_final<<<1, 64, 0, stream>>>(wsu, out);
}

// Round 10
// 236.835 us; speedup vs baseline: 1.0152x; 1.0152x over previous
//
#include <hip/hip_runtime.h>
#include <math.h>

#define HW (512 * 512)
#define NB 16
#define NTHR 256
#define GXS_S 128       // k_stats: 128 blocks/batch * 256 thr * 8 px  (r8: -7%)
#define CH_S 2
#define GXS_P 64        // k_pix:    64 blocks/batch * 256 thr * 16 px (r7 best)
#define CH_P 4
#define ACCW 56         // padded stride of the 53-value per-block partials

// ---- workspace layout (4-byte words). NOTHING is pre-zeroed: every word is
// written unconditionally before it is read (poison-robust). Coherence comes
// from kernel dispatch boundaries only — round-5 lesson: device-scope fences
// (threadfence/tickets) inside hot kernels cost ~2.5x via L2 writeback/inv. ----
#define OFF_ACC    0                              // f [NB][GXS_S][ACCW] k_stats partials
#define OFF_NEGMX  (OFF_ACC + NB * GXS_S * ACCW)  // u [NB][GXS_S] per-block max(~negkey)
#define OFF_PPART  (OFF_NEGMX + NB * GXS_S)       // f [NB][GXS_P][4] k_pix partials
#define OFF_KDICE  (OFF_PPART + NB * GXS_P * 4)   // f [NB][3] ak,bk,ck
#define OFF_NVAL   (OFF_KDICE + NB * 3)           // u [NB]
#define OFF_DISCR  (OFF_NVAL + NB)                // f [NB]

// partial value indices: 0-7 kcnt, 8-15 tcnt, 16-47 ksum, 48 pos,
//                        49 ak, 50 bk, 51 ck, 52 negcnt

__device__ __forceinline__ unsigned fmap(float f) {
    unsigned u = __float_as_uint(f);
    return (u & 0x80000000u) ? ~u : (u | 0x80000000u);
}
__device__ __forceinline__ float funmap(unsigned u) {
    return (u & 0x80000000u) ? __uint_as_float(u & 0x7FFFFFFFu)
                             : __uint_as_float(~u);
}
__device__ __forceinline__ float wred(float x) {
#pragma unroll
    for (int o = 32; o; o >>= 1) x += __shfl_xor(x, o);
    return x;
}
__device__ __forceinline__ unsigned wredumax(unsigned x) {
#pragma unroll
    for (int o = 32; o; o >>= 1) x = max(x, (unsigned)__shfl_xor((int)x, o));
    return x;
}
__device__ __forceinline__ unsigned long long wredull(unsigned long long x) {
#pragma unroll
    for (int o = 32; o; o >>= 1)
        x += (unsigned long long)__shfl_xor((unsigned long long)x, o);
    return x;
}

// ---------------- K1: stats + kernel-dice partials (r8 form, GXS_S=128) ------
__global__ __launch_bounds__(NTHR, 2) void k_stats(const float* __restrict__ preds,
                        const int* __restrict__ text,
                        const int* __restrict__ kern,
                        const int* __restrict__ mask,
                        unsigned* __restrict__ wsu) {
    float* wsf = (float*)wsu;
    const int b = blockIdx.y;
    const int tid = threadIdx.x;
    const int lane = tid & 63;
    __shared__ float sacc[53];
    __shared__ unsigned smx;
    if (tid < 53) sacc[tid] = 0.f;
    if (tid == 0) smx = 0u;
    __syncthreads();

    const int* tb = text + b * HW;
    const int* kb = kern + b * HW;
    const int* mb = mask + b * HW;
    const float* p0 = preds + (size_t)(b * 6 + 0) * HW;
    const float* p1 = preds + (size_t)(b * 6 + 1) * HW;
    const float* e0 = preds + (size_t)(b * 6 + 2) * HW;
    const float* e1 = e0 + HW;
    const float* e2 = e0 + 2 * HW;
    const float* e3 = e0 + 3 * HW;

    unsigned negc = 0u;   // per-thread count of text==0 pixels
    unsigned mkAll = 0u;

    float ks[32];
#pragma unroll
    for (int i = 0; i < 32; i++) ks[i] = 0.f;
    float r_ak = 0.f, r_bk = 0.f, r_ck = 0.f, r_pos = 0.f;
    unsigned kcW[8] = {0, 0, 0, 0, 0, 0, 0, 0};
    unsigned long long tpack = 0ull;  // 8x8-bit per-thread text-counts (<=8/field)

#pragma unroll 1
    for (int c = 0; c < CH_S; c++) {
        const int base = blockIdx.x * (NTHR * 4 * CH_S) + c * (NTHR * 4) + tid * 4;
        const int4 t4 = *(const int4*)(tb + base);
        const int4 k4 = *(const int4*)(kb + base);
        const int4 m4 = *(const int4*)(mb + base);
        const float4 s4 = *(const float4*)(p0 + base);
        const float4 q4 = *(const float4*)(p1 + base);
        const float4 a4 = *(const float4*)(e0 + base);
        const float4 b4 = *(const float4*)(e1 + base);
        const float4 c4 = *(const float4*)(e2 + base);
        const float4 d4 = *(const float4*)(e3 + base);

#define PIX(T, K, M, Q, A, B, C, D) do {                                     \
        bool pos_ = (T) > 0, mp_ = (M) > 0;                                  \
        float sm_ = (pos_ && mp_) ? 1.f : 0.f;                               \
        float sg_ = 1.f / (1.f + expf(-(Q)));                                \
        float ik_ = ((K) > 0) ? 1.f : 0.f;                                   \
        r_ak += sm_ * sg_ * ik_;                                             \
        r_bk += sm_ * sg_ * sg_;                                             \
        r_ck += sm_ * ik_;                                                   \
        r_pos += sm_;                                                        \
        tpack += pos_ ? (1ull << ((((unsigned)(T) - 1u) & 7u) * 8u)) : 0ull; \
        _Pragma("unroll")                                                    \
        for (int i_ = 0; i_ < 8; i_++) {                                     \
            bool hit_ = ((K) == i_ + 1);                                     \
            kcW[i_] += (unsigned)__popcll(__ballot(hit_));                   \
            float h_ = hit_ ? 1.f : 0.f;                                     \
            ks[i_ * 4 + 0] += h_ * (A);                                      \
            ks[i_ * 4 + 1] += h_ * (B);                                      \
            ks[i_ * 4 + 2] += h_ * (C);                                      \
            ks[i_ * 4 + 3] += h_ * (D);                                      \
        }                                                                    \
    } while (0)

        PIX(t4.x, k4.x, m4.x, q4.x, a4.x, b4.x, c4.x, d4.x);
        PIX(t4.y, k4.y, m4.y, q4.y, a4.y, b4.y, c4.y, d4.y);
        PIX(t4.z, k4.z, m4.z, q4.z, a4.z, b4.z, c4.z, d4.z);
        PIX(t4.w, k4.w, m4.w, q4.w, a4.w, b4.w, c4.w, d4.w);
#undef PIX

        // ---- per-thread negative count + min negative score (no ballots) ----
        negc += (unsigned)(t4.x == 0) + (unsigned)(t4.y == 0)
              + (unsigned)(t4.z == 0) + (unsigned)(t4.w == 0);
        unsigned mk = 0u;
        if (t4.x == 0) mk = max(mk, ~fmap(s4.x));
        if (t4.y == 0) mk = max(mk, ~fmap(s4.y));
        if (t4.z == 0) mk = max(mk, ~fmap(s4.z));
        if (t4.w == 0) mk = max(mk, ~fmap(s4.w));
        mkAll = max(mkAll, mk);
    }

    mkAll = wredumax(mkAll);
    if (lane == 0) atomicMax(&smx, mkAll);

    // ---- epilogue: wave butterfly -> LDS -> plain per-block store ----
#pragma unroll
    for (int i = 0; i < 32; i++) {
        float v = wred(ks[i]);
        if (lane == 0) atomicAdd(&sacc[16 + i], v);
    }
    {
        float v = wred(r_ak); if (lane == 0) atomicAdd(&sacc[49], v);
        v = wred(r_bk); if (lane == 0) atomicAdd(&sacc[50], v);
        v = wred(r_ck); if (lane == 0) atomicAdd(&sacc[51], v);
        v = wred(r_pos); if (lane == 0) atomicAdd(&sacc[48], v);
        unsigned nv = negc;   // per-thread counts -> butterfly is correct here
#pragma unroll
        for (int o = 32; o; o >>= 1) nv += (unsigned)__shfl_xor((int)nv, o);
        if (lane == 0) atomicAdd(&sacc[52], (float)nv);
    }
    {
        // unpack 8x8-bit -> 2x(4x16-bit) so the 64-lane sum can't overflow
        unsigned long long lo = tpack & 0x00FF00FF00FF00FFull;          // inst 1,3,5,7
        unsigned long long hi = (tpack >> 8) & 0x00FF00FF00FF00FFull;   // inst 2,4,6,8
        lo = wredull(lo);
        hi = wredull(hi);
        if (lane == 0) {
            atomicAdd(&sacc[8 + 0], (float)(unsigned)( lo        & 0xFFFFull));
            atomicAdd(&sacc[8 + 2], (float)(unsigned)((lo >> 16) & 0xFFFFull));
            atomicAdd(&sacc[8 + 4], (float)(unsigned)((lo >> 32) & 0xFFFFull));
            atomicAdd(&sacc[8 + 6], (float)(unsigned)((lo >> 48) & 0xFFFFull));
            atomicAdd(&sacc[8 + 1], (float)(unsigned)( hi        & 0xFFFFull));
            atomicAdd(&sacc[8 + 3], (float)(unsigned)((hi >> 16) & 0xFFFFull));
            atomicAdd(&sacc[8 + 5], (float)(unsigned)((hi >> 32) & 0xFFFFull));
            atomicAdd(&sacc[8 + 7], (float)(unsigned)((hi >> 48) & 0xFFFFull));
        }
    }
    if (lane == 0) {
#pragma unroll
        for (int i = 0; i < 8; i++) atomicAdd(&sacc[i], (float)kcW[i]);
    }
    __syncthreads();
    if (tid < 53)
        wsf[OFF_ACC + (b * GXS_S + blockIdx.x) * ACCW + tid] = sacc[tid];
    if (tid == 0)
        wsu[OFF_NEGMX + b * GXS_S + blockIdx.x] = smx;
}

// ---------------- K2: redundant per-batch setup + aggregation + OHEM dice ----
// r7 form (GXS_P=64, 16 px/thread — its measured optimum) with the preamble
// reading the GXS_S=128 k_stats partials (identical sums to r8's passing run).
__global__ __launch_bounds__(NTHR, 2) void k_pix(const float* __restrict__ preds,
                      const int* __restrict__ text,
                      const int* __restrict__ mask,
                      unsigned* __restrict__ wsu) {
    float* wsf = (float*)wsu;
    const int b = blockIdx.y;
    const int tid = threadIdx.x;
    const int lane = tid & 63;
    __shared__ float s_sum[53];
    __shared__ float stbl[45];
    __shared__ int s_valid[8];
    __shared__ unsigned s_negmax;
    __shared__ float s_thr;
    __shared__ int s_fb;
    __shared__ unsigned s_kk, s_prefix;
    __shared__ unsigned s_hist[256];
    __shared__ float sred[4];

    const int* tb = text + b * HW;
    const int* mb = mask + b * HW;
    const float* p0 = preds + (size_t)(b * 6) * HW;
    const float* e0 = preds + (size_t)(b * 6 + 2) * HW;
    const float* e1 = e0 + HW;
    const float* e2 = e0 + 2 * HW;
    const float* e3 = e0 + 3 * HW;

    // ---- preamble: recompute batch setup from partials ----
    if (tid < 53) {
        float v = 0.f;
        const float* p = wsf + OFF_ACC + (size_t)b * GXS_S * ACCW + tid;
        for (int r = 0; r < GXS_S; r++) v += p[r * ACCW];
        s_sum[tid] = v;
    }
    if (tid >= 64 && tid < 128) {
        // 64 threads cover GXS_S=128 entries, 2 each
        unsigned m = max(wsu[OFF_NEGMX + b * GXS_S + (tid - 64)],
                         wsu[OFF_NEGMX + b * GXS_S + (tid - 64) + 64]);
        m = wredumax(m);
        if (tid == 64) s_negmax = m;
    }
    if (tid < 4) sred[tid] = 0.f;
    __syncthreads();
    if (tid < 8) {
        float kcf = s_sum[tid];
        float tcf = s_sum[8 + tid];
        int valid = (kcf > 0.f && tcf > 0.f) ? 1 : 0;
        s_valid[tid] = valid;
        float inv = 1.f / fmaxf(kcf, 1.f);
        float w = valid ? 1.f / fmaxf(tcf, 1.f) : 0.f;
#pragma unroll
        for (int c = 0; c < 4; c++)
            stbl[(tid + 1) * 5 + c] = s_sum[16 + tid * 4 + c] * inv;
        stbl[(tid + 1) * 5 + 4] = w;
    }
    if (tid >= 8 && tid < 13) stbl[tid - 8] = 0.f;   // bg row
    __syncthreads();
    if (tid == 0) {
        unsigned pos = (unsigned)s_sum[48];
        unsigned neg = (unsigned)s_sum[52];
        unsigned nn = min(pos * 3u, neg);
        int fb = (pos == 0u || nn == 0u) ? 1 : 0;
        s_fb = fb;
        unsigned kk = fb ? 0u : nn;
        float thr = 0.f;
        if (!fb && nn == neg) {           // fast path: min negative score
            thr = funmap(~s_negmax);
            kk = 0u;
        }
        s_thr = thr;
        s_kk = kk;
        s_prefix = 0u;
    }
    // bx==0 block: housekeeping for k_final
    if (blockIdx.x == 0) {
        if (tid >= 16 && tid < 19)
            wsf[OFF_KDICE + b * 3 + (tid - 16)] = s_sum[49 + (tid - 16)];
        if (tid == 32) {
            int nval = 0;
            for (int i = 0; i < 8; i++) nval += s_valid[i];
            wsu[OFF_NVAL + b] = (unsigned)nval;
            float L = 0.f;
            for (int i = 0; i < 8; i++)
                for (int j = i + 1; j < 8; j++)
                    if (s_valid[i] && s_valid[j]) {
                        float sq = 0.f;
                        for (int c = 0; c < 4; c++) {
                            float d = stbl[(i + 1) * 5 + c] - stbl[(j + 1) * 5 + c];
                            sq += d * d;
                        }
                        float h = fmaxf(3.0f - sqrtf(sq), 0.f);
                        L += log1pf(h * h);
                    }
            wsf[OFF_DISCR + b] = (nval > 1) ? L / fmaxf((float)(nval * (nval - 1)), 1.f) : 0.f;
        }
    }
    __syncthreads();
    // rare fallback: per-block radix select over raw preds (correct, slow,
    // never taken on fast-path data)
    if (s_kk != 0u) {
        unsigned prefix = 0u;
        for (int pass = 0; pass < 4; pass++) {
            const int shift = 24 - 8 * pass;
            const unsigned fmask = (pass == 0) ? 0u : (0xFFFFFFFFu << (shift + 8));
            s_hist[tid] = 0u;
            __syncthreads();
            for (int p = tid; p < HW; p += NTHR) {
                if (tb[p] == 0) {
                    unsigned key = fmap(p0[p]);
                    if ((key & fmask) == prefix) atomicAdd(&s_hist[(key >> shift) & 255u], 1u);
                }
            }
            __syncthreads();
            if (tid == 0) {
                unsigned k2 = s_kk;
                for (int bin = 255; bin >= 0; --bin) {
                    unsigned c = s_hist[bin];
                    if (k2 <= c) { s_prefix = prefix | (((unsigned)bin) << shift); s_kk = k2; break; }
                    k2 -= c;
                }
            }
            __syncthreads();
            prefix = s_prefix;
        }
        if (tid == 0) s_thr = funmap(prefix);
        __syncthreads();
    }
    const float thr = s_thr;
    const bool fb = s_fb != 0;

    // ---- main loop: r7 body (16 px/thread) ----
    float r_at = 0.f, r_bt = 0.f, r_ct = 0.f, r_ag = 0.f;
#pragma unroll 1
    for (int c = 0; c < CH_P; c++) {
        const int base = blockIdx.x * (NTHR * 4 * CH_P) + c * (NTHR * 4) + tid * 4;
        const int4 t4 = *(const int4*)(tb + base);
        const int4 m4 = *(const int4*)(mb + base);
        const float4 s4 = *(const float4*)(p0 + base);
        const float4 a4 = *(const float4*)(e0 + base);
        const float4 b4 = *(const float4*)(e1 + base);
        const float4 c4 = *(const float4*)(e2 + base);
        const float4 d4 = *(const float4*)(e3 + base);

#define PPIX(T, M, S, A, B, C, D) do {                                       \
        bool pos_ = (T) > 0;                                                 \
        bool samp_ = fb ? ((M) > 0) : ((((S) >= thr) || pos_) && ((M) > 0)); \
        float sg_ = 1.f / (1.f + expf(-(S)));                                \
        float smf_ = samp_ ? 1.f : 0.f;                                      \
        float it_ = pos_ ? 1.f : 0.f;                                        \
        r_at += smf_ * sg_ * it_;                                            \
        r_bt += smf_ * sg_ * sg_;                                            \
        r_ct += smf_ * it_;                                                  \
        int t5_ = min((T), 8) * 5;                                           \
        float d0_ = (A) - stbl[t5_ + 0];                                     \
        float d1_ = (B) - stbl[t5_ + 1];                                     \
        float d2_ = (C) - stbl[t5_ + 2];                                     \
        float d3_ = (D) - stbl[t5_ + 3];                                     \
        float w_ = stbl[t5_ + 4];                                            \
        float sq_ = d0_ * d0_ + d1_ * d1_ + d2_ * d2_ + d3_ * d3_;           \
        float dist_ = sqrtf(sq_ + 1e-12f) - 0.5f;                            \
        float hp_ = fmaxf(dist_, 0.f);                                       \
        r_ag += w_ * log1pf(hp_ * hp_);                                      \
    } while (0)

        PPIX(t4.x, m4.x, s4.x, a4.x, b4.x, c4.x, d4.x);
        PPIX(t4.y, m4.y, s4.y, a4.y, b4.y, c4.y, d4.y);
        PPIX(t4.z, m4.z, s4.z, a4.z, b4.z, c4.z, d4.z);
        PPIX(t4.w, m4.w, s4.w, a4.w, b4.w, c4.w, d4.w);
#undef PPIX
    }

    {
        float v = wred(r_at); if (lane == 0) atomicAdd(&sred[0], v);
        v = wred(r_bt); if (lane == 0) atomicAdd(&sred[1], v);
        v = wred(r_ct); if (lane == 0) atomicAdd(&sred[2], v);
        v = wred(r_ag); if (lane == 0) atomicAdd(&sred[3], v);
    }
    __syncthreads();
    if (tid < 4)
        wsf[OFF_PPART + (b * GXS_P + blockIdx.x) * 4 + tid] = sred[tid];
}

// ---------------- K3: final assembly (r7 form, GXS_P partials) ----------------
__global__ void k_final(unsigned* __restrict__ wsu, float* __restrict__ out) {
    float* wsf = (float*)wsu;
    __shared__ float sfin[64];
    __shared__ float lt[NB], lk[NB], la[NB], ld[NB];
    const int tid = threadIdx.x;   // 64 threads
    {
        const int bb = tid >> 2, v = tid & 3;
        float s = 0.f;
        const float* p = wsf + OFF_PPART + (size_t)bb * GXS_P * 4 + v;
        for (int r = 0; r < GXS_P; r++) s += p[r * 4];
        sfin[tid] = s;
    }
    __syncthreads();
    if (tid < NB) {
        const float S = 1e-3f;
        float at = sfin[tid * 4 + 0], bt = sfin[tid * 4 + 1];
        float ct = sfin[tid * 4 + 2], ag = sfin[tid * 4 + 3];
        float ak = wsf[OFF_KDICE + tid * 3 + 0];
        float bk = wsf[OFF_KDICE + tid * 3 + 1];
        float ck = wsf[OFF_KDICE + tid * 3 + 2];
        lt[tid] = 1.f - 2.f * (at + S) / ((bt + S) + (ct + S));
        lk[tid] = 1.f - 2.f * (ak + S) / ((bk + S) + (ck + S));
        int nval = (int)wsu[OFF_NVAL + tid];
        la[tid] = (nval > 0) ? ag / fmaxf((float)nval, 1.f) : 0.f;
        ld[tid] = wsf[OFF_DISCR + tid];
    }
    __syncthreads();
    if (tid == 0) {
        float st = 0, sk = 0, sa = 0, sd = 0;
        for (int i = 0; i < NB; i++) { st += lt[i]; sk += lk[i]; sa += la[i]; sd += ld[i]; }
        out[0] = st / NB;
        out[1] = 0.5f * sk / NB;
        out[2] = 0.25f * sa / NB;
        out[3] = 0.25f * sd / NB;
    }
}

extern "C" void kernel_launch(void* const* d_in, const int* in_sizes, int n_in,
                              void* d_out, int out_size, void* d_ws, size_t ws_size,
                              hipStream_t stream) {
    const float* preds = (const float*)d_in[0];
    const int* text = (const int*)d_in[1];
    const int* kern = (const int*)d_in[2];
    const int* mask = (const int*)d_in[3];
    unsigned* wsu = (unsigned*)d_ws;
    float* out = (float*)d_out;

    dim3 grid_s(GXS_S, NB);
    dim3 grid_p(GXS_P, NB);
    k_stats<<<grid_s, NTHR, 0, stream>>>(preds, text, kern, mask, wsu);
    k_pix<<<grid_p, NTHR, 0, stream>>>(preds, text, mask, wsu);
    k_final<<<1, 64, 0, stream>>>(wsu, out);
}

// Round 11
// 227.686 us; speedup vs baseline: 1.0560x; 1.0402x over previous
//
#include <hip/hip_runtime.h>
#include <math.h>

#define HW (512 * 512)
#define NB 16
#define NTHR 256
#define GXS_S 128       // k_stats: 128 blocks/batch * 256 thr * 8 px  (r8: -7%)
#define CH_S 2
#define GXS_P 64        // k_pix:    64 blocks/batch * 256 thr * 16 px (r7 best)
#define CH_P 4
#define ACCW 56         // padded stride of the 53-value per-block partials

// ---- workspace layout (4-byte words). NOTHING is pre-zeroed: every word is
// written unconditionally before it is read (poison-robust). Coherence comes
// from kernel dispatch boundaries only — round-5 lesson: device-scope fences
// (threadfence/tickets) inside hot kernels cost ~2.5x via L2 writeback/inv.
// Round-11 lesson (math, not counters): on the fast path (nn==neg) the OHEM
// threshold = min negative score and samp ≡ maskpos — so k_stats need not read
// the score stream at all (9 -> 8 streams) and no negmax machinery is needed. ----
#define OFF_ACC    0                              // f [NB][GXS_S][ACCW] k_stats partials
#define OFF_PPART  (OFF_ACC + NB * GXS_S * ACCW)  // f [NB][GXS_P][4] k_pix partials
#define OFF_KDICE  (OFF_PPART + NB * GXS_P * 4)   // f [NB][3] ak,bk,ck
#define OFF_NVAL   (OFF_KDICE + NB * 3)           // u [NB]
#define OFF_DISCR  (OFF_NVAL + NB)                // f [NB]

// partial value indices: 0-7 kcnt, 8-15 tcnt, 16-47 ksum, 48 pos,
//                        49 ak, 50 bk, 51 ck, 52 negcnt

__device__ __forceinline__ unsigned fmap(float f) {
    unsigned u = __float_as_uint(f);
    return (u & 0x80000000u) ? ~u : (u | 0x80000000u);
}
__device__ __forceinline__ float funmap(unsigned u) {
    return (u & 0x80000000u) ? __uint_as_float(u & 0x7FFFFFFFu)
                             : __uint_as_float(~u);
}
__device__ __forceinline__ float wred(float x) {
#pragma unroll
    for (int o = 32; o; o >>= 1) x += __shfl_xor(x, o);
    return x;
}
__device__ __forceinline__ unsigned long long wredull(unsigned long long x) {
#pragma unroll
    for (int o = 32; o; o >>= 1)
        x += (unsigned long long)__shfl_xor((unsigned long long)x, o);
    return x;
}

// ---------------- K1: stats + kernel-dice partials (8 streams) ----------------
__global__ __launch_bounds__(NTHR, 2) void k_stats(const float* __restrict__ preds,
                        const int* __restrict__ text,
                        const int* __restrict__ kern,
                        const int* __restrict__ mask,
                        unsigned* __restrict__ wsu) {
    float* wsf = (float*)wsu;
    const int b = blockIdx.y;
    const int tid = threadIdx.x;
    const int lane = tid & 63;
    __shared__ float sacc[53];
    if (tid < 53) sacc[tid] = 0.f;
    __syncthreads();

    const int* tb = text + b * HW;
    const int* kb = kern + b * HW;
    const int* mb = mask + b * HW;
    const float* p1 = preds + (size_t)(b * 6 + 1) * HW;
    const float* e0 = preds + (size_t)(b * 6 + 2) * HW;
    const float* e1 = e0 + HW;
    const float* e2 = e0 + 2 * HW;
    const float* e3 = e0 + 3 * HW;

    unsigned negc = 0u;   // per-thread count of text==0 pixels

    float ks[32];
#pragma unroll
    for (int i = 0; i < 32; i++) ks[i] = 0.f;
    float r_ak = 0.f, r_bk = 0.f, r_ck = 0.f, r_pos = 0.f;
    unsigned kcW[8] = {0, 0, 0, 0, 0, 0, 0, 0};
    unsigned long long tpack = 0ull;  // 8x8-bit per-thread text-counts (<=8/field)

#pragma unroll 1
    for (int c = 0; c < CH_S; c++) {
        const int base = blockIdx.x * (NTHR * 4 * CH_S) + c * (NTHR * 4) + tid * 4;
        const int4 t4 = *(const int4*)(tb + base);
        const int4 k4 = *(const int4*)(kb + base);
        const int4 m4 = *(const int4*)(mb + base);
        const float4 q4 = *(const float4*)(p1 + base);
        const float4 a4 = *(const float4*)(e0 + base);
        const float4 b4 = *(const float4*)(e1 + base);
        const float4 c4 = *(const float4*)(e2 + base);
        const float4 d4 = *(const float4*)(e3 + base);

#define PIX(T, K, M, Q, A, B, C, D) do {                                     \
        bool pos_ = (T) > 0, mp_ = (M) > 0;                                  \
        float sm_ = (pos_ && mp_) ? 1.f : 0.f;                               \
        float sg_ = 1.f / (1.f + expf(-(Q)));                                \
        float ik_ = ((K) > 0) ? 1.f : 0.f;                                   \
        r_ak += sm_ * sg_ * ik_;                                             \
        r_bk += sm_ * sg_ * sg_;                                             \
        r_ck += sm_ * ik_;                                                   \
        r_pos += sm_;                                                        \
        tpack += pos_ ? (1ull << ((((unsigned)(T) - 1u) & 7u) * 8u)) : 0ull; \
        _Pragma("unroll")                                                    \
        for (int i_ = 0; i_ < 8; i_++) {                                     \
            bool hit_ = ((K) == i_ + 1);                                     \
            kcW[i_] += (unsigned)__popcll(__ballot(hit_));                   \
            float h_ = hit_ ? 1.f : 0.f;                                     \
            ks[i_ * 4 + 0] += h_ * (A);                                      \
            ks[i_ * 4 + 1] += h_ * (B);                                      \
            ks[i_ * 4 + 2] += h_ * (C);                                      \
            ks[i_ * 4 + 3] += h_ * (D);                                      \
        }                                                                    \
    } while (0)

        PIX(t4.x, k4.x, m4.x, q4.x, a4.x, b4.x, c4.x, d4.x);
        PIX(t4.y, k4.y, m4.y, q4.y, a4.y, b4.y, c4.y, d4.y);
        PIX(t4.z, k4.z, m4.z, q4.z, a4.z, b4.z, c4.z, d4.z);
        PIX(t4.w, k4.w, m4.w, q4.w, a4.w, b4.w, c4.w, d4.w);
#undef PIX

        // ---- per-thread negative count (no score stream needed) ----
        negc += (unsigned)(t4.x == 0) + (unsigned)(t4.y == 0)
              + (unsigned)(t4.z == 0) + (unsigned)(t4.w == 0);
    }

    // ---- epilogue: wave butterfly -> LDS -> plain per-block store ----
#pragma unroll
    for (int i = 0; i < 32; i++) {
        float v = wred(ks[i]);
        if (lane == 0) atomicAdd(&sacc[16 + i], v);
    }
    {
        float v = wred(r_ak); if (lane == 0) atomicAdd(&sacc[49], v);
        v = wred(r_bk); if (lane == 0) atomicAdd(&sacc[50], v);
        v = wred(r_ck); if (lane == 0) atomicAdd(&sacc[51], v);
        v = wred(r_pos); if (lane == 0) atomicAdd(&sacc[48], v);
        unsigned nv = negc;   // per-thread counts -> butterfly is correct here
#pragma unroll
        for (int o = 32; o; o >>= 1) nv += (unsigned)__shfl_xor((int)nv, o);
        if (lane == 0) atomicAdd(&sacc[52], (float)nv);
    }
    {
        // unpack 8x8-bit -> 2x(4x16-bit) so the 64-lane sum can't overflow
        unsigned long long lo = tpack & 0x00FF00FF00FF00FFull;          // inst 1,3,5,7
        unsigned long long hi = (tpack >> 8) & 0x00FF00FF00FF00FFull;   // inst 2,4,6,8
        lo = wredull(lo);
        hi = wredull(hi);
        if (lane == 0) {
            atomicAdd(&sacc[8 + 0], (float)(unsigned)( lo        & 0xFFFFull));
            atomicAdd(&sacc[8 + 2], (float)(unsigned)((lo >> 16) & 0xFFFFull));
            atomicAdd(&sacc[8 + 4], (float)(unsigned)((lo >> 32) & 0xFFFFull));
            atomicAdd(&sacc[8 + 6], (float)(unsigned)((lo >> 48) & 0xFFFFull));
            atomicAdd(&sacc[8 + 1], (float)(unsigned)( hi        & 0xFFFFull));
            atomicAdd(&sacc[8 + 3], (float)(unsigned)((hi >> 16) & 0xFFFFull));
            atomicAdd(&sacc[8 + 5], (float)(unsigned)((hi >> 32) & 0xFFFFull));
            atomicAdd(&sacc[8 + 7], (float)(unsigned)((hi >> 48) & 0xFFFFull));
        }
    }
    if (lane == 0) {
#pragma unroll
        for (int i = 0; i < 8; i++) atomicAdd(&sacc[i], (float)kcW[i]);
    }
    __syncthreads();
    if (tid < 53)
        wsf[OFF_ACC + (b * GXS_S + blockIdx.x) * ACCW + tid] = sacc[tid];
}

// ---------------- K2: redundant per-batch setup + aggregation + OHEM dice ----
// Fast path (nn==neg, always on this data): samp ≡ maskpos — no threshold, no
// negmax. Rare non-uniform case computes thr via per-block radix over raw preds.
__global__ __launch_bounds__(NTHR, 2) void k_pix(const float* __restrict__ preds,
                      const int* __restrict__ text,
                      const int* __restrict__ mask,
                      unsigned* __restrict__ wsu) {
    float* wsf = (float*)wsu;
    const int b = blockIdx.y;
    const int tid = threadIdx.x;
    const int lane = tid & 63;
    __shared__ float s_sum[53];
    __shared__ float stbl[45];
    __shared__ int s_valid[8];
    __shared__ float s_thr;
    __shared__ int s_uni;
    __shared__ unsigned s_kk, s_prefix;
    __shared__ unsigned s_hist[256];
    __shared__ float sred[4];

    const int* tb = text + b * HW;
    const int* mb = mask + b * HW;
    const float* p0 = preds + (size_t)(b * 6) * HW;
    const float* e0 = preds + (size_t)(b * 6 + 2) * HW;
    const float* e1 = e0 + HW;
    const float* e2 = e0 + 2 * HW;
    const float* e3 = e0 + 3 * HW;

    // ---- preamble: recompute batch setup from partials ----
    if (tid < 53) {
        float v = 0.f;
        const float* p = wsf + OFF_ACC + (size_t)b * GXS_S * ACCW + tid;
        for (int r = 0; r < GXS_S; r++) v += p[r * ACCW];
        s_sum[tid] = v;
    }
    if (tid < 4) sred[tid] = 0.f;
    __syncthreads();
    if (tid < 8) {
        float kcf = s_sum[tid];
        float tcf = s_sum[8 + tid];
        int valid = (kcf > 0.f && tcf > 0.f) ? 1 : 0;
        s_valid[tid] = valid;
        float inv = 1.f / fmaxf(kcf, 1.f);
        float w = valid ? 1.f / fmaxf(tcf, 1.f) : 0.f;
#pragma unroll
        for (int c = 0; c < 4; c++)
            stbl[(tid + 1) * 5 + c] = s_sum[16 + tid * 4 + c] * inv;
        stbl[(tid + 1) * 5 + 4] = w;
    }
    if (tid >= 8 && tid < 13) stbl[tid - 8] = 0.f;   // bg row
    __syncthreads();
    if (tid == 0) {
        unsigned pos = (unsigned)s_sum[48];
        unsigned neg = (unsigned)s_sum[52];
        unsigned nn = min(pos * 3u, neg);
        // uniform: fallback (no pos / no neg) OR all negatives selected —
        // in both cases samp ≡ maskpos and no threshold is needed.
        int uni = (pos == 0u || nn == 0u || nn == neg) ? 1 : 0;
        s_uni = uni;
        s_kk = uni ? 0u : nn;
        s_thr = 0.f;
        s_prefix = 0u;
    }
    // bx==0 block: housekeeping for k_final
    if (blockIdx.x == 0) {
        if (tid >= 16 && tid < 19)
            wsf[OFF_KDICE + b * 3 + (tid - 16)] = s_sum[49 + (tid - 16)];
        if (tid == 32) {
            int nval = 0;
            for (int i = 0; i < 8; i++) nval += s_valid[i];
            wsu[OFF_NVAL + b] = (unsigned)nval;
            float L = 0.f;
            for (int i = 0; i < 8; i++)
                for (int j = i + 1; j < 8; j++)
                    if (s_valid[i] && s_valid[j]) {
                        float sq = 0.f;
                        for (int c = 0; c < 4; c++) {
                            float d = stbl[(i + 1) * 5 + c] - stbl[(j + 1) * 5 + c];
                            sq += d * d;
                        }
                        float h = fmaxf(3.0f - sqrtf(sq), 0.f);
                        L += log1pf(h * h);
                    }
            wsf[OFF_DISCR + b] = (nval > 1) ? L / fmaxf((float)(nval * (nval - 1)), 1.f) : 0.f;
        }
    }
    __syncthreads();
    // rare non-uniform case: per-block radix select over raw preds
    if (s_kk != 0u) {
        unsigned prefix = 0u;
        for (int pass = 0; pass < 4; pass++) {
            const int shift = 24 - 8 * pass;
            const unsigned fmask = (pass == 0) ? 0u : (0xFFFFFFFFu << (shift + 8));
            s_hist[tid] = 0u;
            __syncthreads();
            for (int p = tid; p < HW; p += NTHR) {
                if (tb[p] == 0) {
                    unsigned key = fmap(p0[p]);
                    if ((key & fmask) == prefix) atomicAdd(&s_hist[(key >> shift) & 255u], 1u);
                }
            }
            __syncthreads();
            if (tid == 0) {
                unsigned k2 = s_kk;
                for (int bin = 255; bin >= 0; --bin) {
                    unsigned c = s_hist[bin];
                    if (k2 <= c) { s_prefix = prefix | (((unsigned)bin) << shift); s_kk = k2; break; }
                    k2 -= c;
                }
            }
            __syncthreads();
            prefix = s_prefix;
        }
        if (tid == 0) s_thr = funmap(prefix);
        __syncthreads();
    }
    const float thr = s_thr;
    const bool uni = s_uni != 0;

    // ---- main loop: r7 body (16 px/thread) ----
    float r_at = 0.f, r_bt = 0.f, r_ct = 0.f, r_ag = 0.f;
#pragma unroll 1
    for (int c = 0; c < CH_P; c++) {
        const int base = blockIdx.x * (NTHR * 4 * CH_P) + c * (NTHR * 4) + tid * 4;
        const int4 t4 = *(const int4*)(tb + base);
        const int4 m4 = *(const int4*)(mb + base);
        const float4 s4 = *(const float4*)(p0 + base);
        const float4 a4 = *(const float4*)(e0 + base);
        const float4 b4 = *(const float4*)(e1 + base);
        const float4 c4 = *(const float4*)(e2 + base);
        const float4 d4 = *(const float4*)(e3 + base);

#define PPIX(T, M, S, A, B, C, D) do {                                       \
        bool pos_ = (T) > 0;                                                 \
        bool samp_ = uni ? ((M) > 0) : ((((S) >= thr) || pos_) && ((M) > 0)); \
        float sg_ = 1.f / (1.f + expf(-(S)));                                \
        float smf_ = samp_ ? 1.f : 0.f;                                      \
        float it_ = pos_ ? 1.f : 0.f;                                        \
        r_at += smf_ * sg_ * it_;                                            \
        r_bt += smf_ * sg_ * sg_;                                            \
        r_ct += smf_ * it_;                                                  \
        int t5_ = min((T), 8) * 5;                                           \
        float d0_ = (A) - stbl[t5_ + 0];                                     \
        float d1_ = (B) - stbl[t5_ + 1];                                     \
        float d2_ = (C) - stbl[t5_ + 2];                                     \
        float d3_ = (D) - stbl[t5_ + 3];                                     \
        float w_ = stbl[t5_ + 4];                                            \
        float sq_ = d0_ * d0_ + d1_ * d1_ + d2_ * d2_ + d3_ * d3_;           \
        float dist_ = sqrtf(sq_ + 1e-12f) - 0.5f;                            \
        float hp_ = fmaxf(dist_, 0.f);                                       \
        r_ag += w_ * log1pf(hp_ * hp_);                                      \
    } while (0)

        PPIX(t4.x, m4.x, s4.x, a4.x, b4.x, c4.x, d4.x);
        PPIX(t4.y, m4.y, s4.y, a4.y, b4.y, c4.y, d4.y);
        PPIX(t4.z, m4.z, s4.z, a4.z, b4.z, c4.z, d4.z);
        PPIX(t4.w, m4.w, s4.w, a4.w, b4.w, c4.w, d4.w);
#undef PPIX
    }

    {
        float v = wred(r_at); if (lane == 0) atomicAdd(&sred[0], v);
        v = wred(r_bt); if (lane == 0) atomicAdd(&sred[1], v);
        v = wred(r_ct); if (lane == 0) atomicAdd(&sred[2], v);
        v = wred(r_ag); if (lane == 0) atomicAdd(&sred[3], v);
    }
    __syncthreads();
    if (tid < 4)
        wsf[OFF_PPART + (b * GXS_P + blockIdx.x) * 4 + tid] = sred[tid];
}

// ---------------- K3: final assembly (GXS_P partials) ----------------
__global__ void k_final(unsigned* __restrict__ wsu, float* __restrict__ out) {
    float* wsf = (float*)wsu;
    __shared__ float sfin[64];
    __shared__ float lt[NB], lk[NB], la[NB], ld[NB];
    const int tid = threadIdx.x;   // 64 threads
    {
        const int bb = tid >> 2, v = tid & 3;
        float s = 0.f;
        const float* p = wsf + OFF_PPART + (size_t)bb * GXS_P * 4 + v;
        for (int r = 0; r < GXS_P; r++) s += p[r * 4];
        sfin[tid] = s;
    }
    __syncthreads();
    if (tid < NB) {
        const float S = 1e-3f;
        float at = sfin[tid * 4 + 0], bt = sfin[tid * 4 + 1];
        float ct = sfin[tid * 4 + 2], ag = sfin[tid * 4 + 3];
        float ak = wsf[OFF_KDICE + tid * 3 + 0];
        float bk = wsf[OFF_KDICE + tid * 3 + 1];
        float ck = wsf[OFF_KDICE + tid * 3 + 2];
        lt[tid] = 1.f - 2.f * (at + S) / ((bt + S) + (ct + S));
        lk[tid] = 1.f - 2.f * (ak + S) / ((bk + S) + (ck + S));
        int nval = (int)wsu[OFF_NVAL + tid];
        la[tid] = (nval > 0) ? ag / fmaxf((float)nval, 1.f) : 0.f;
        ld[tid] = wsf[OFF_DISCR + tid];
    }
    __syncthreads();
    if (tid == 0) {
        float st = 0, sk = 0, sa = 0, sd = 0;
        for (int i = 0; i < NB; i++) { st += lt[i]; sk += lk[i]; sa += la[i]; sd += ld[i]; }
        out[0] = st / NB;
        out[1] = 0.5f * sk / NB;
        out[2] = 0.25f * sa / NB;
        out[3] = 0.25f * sd / NB;
    }
}

extern "C" void kernel_launch(void* const* d_in, const int* in_sizes, int n_in,
                              void* d_out, int out_size, void* d_ws, size_t ws_size,
                              hipStream_t stream) {
    const float* preds = (const float*)d_in[0];
    const int* text = (const int*)d_in[1];
    const int* kern = (const int*)d_in[2];
    const int* mask = (const int*)d_in[3];
    unsigned* wsu = (unsigned*)d_ws;
    float* out = (float*)d_out;

    dim3 grid_s(GXS_S, NB);
    dim3 grid_p(GXS_P, NB);
    k_stats<<<grid_s, NTHR, 0, stream>>>(preds, text, kern, mask, wsu);
    k_pix<<<grid_p, NTHR, 0, stream>>>(preds, text, mask, wsu);
    k_final<<<1, 64, 0, stream>>>(wsu, out);
}